// Round 10
// baseline (50.542 us; speedup 1.0000x reference)
//
#include <hip/hip_runtime.h>
#include <math.h>

// (B,T,C)=(16,2048,1024), H=16, K=31, R=64, causal pad P=30.
// out[b,t,c] = sum_{j=0..30} w_rev[h(c),j] * x[b,t-j,c],  w_rev[j] = softmax(w)[30-j]
//
// Wave-level rolling pipeline: block = ONE wave owning 512 t-rows of one head.
// 16 tiles x 32 rows; 3-slot LDS ring (3 x 32 rows x 256 B = 24 KB) of chunks
// C_j = rows [ts+32j, ts+32j+32). Tile j reads C_{j-1} (slot A) + C_j (slot B)
// while chunk C_{j+1} DMA-streams into slot N. Counted vmcnt(16) -> the wave
// ALWAYS has DMA + stores in flight while issuing FMAs (R5-R9 all serialized
// {DMA drain -> compute -> store burst} per wave: 72% memory-wait, 4.3 TB/s).
#define TPB   64
#define KW    31
#define HALO  30
#define TT    8                 // output rows per thread per tile (float4-wide)
#define CH    32                // rows per chunk/tile
#define SEG   512               // rows per wave task
#define NTILE (SEG / CH)        // 16
constexpr int B_ = 16, T_ = 2048, C_ = 1024, H_ = 16;
constexpr int C4 = C_ / 4;      // float4 per t-row (256)

typedef float f32x4 __attribute__((ext_vector_type(4)));

__device__ inline float rfl(float v) {   // lane-uniform float -> SGPR
    return __builtin_bit_cast(float, __builtin_amdgcn_readfirstlane(__builtin_bit_cast(int, v)));
}

__global__ __launch_bounds__(TPB) void lconv_kernel(const float* __restrict__ x,
                                                    const float* __restrict__ w,
                                                    float* __restrict__ out) {
    __shared__ float smem[3 * CH * 64];      // 3 slots x 8 KB = 24 KB (4 blocks/CU)
    const int h    = blockIdx.x;
    const int seg  = blockIdx.y;
    const int b    = blockIdx.z;
    const int ts   = seg * SEG;
    const int lane = threadIdx.x;
    const int qrow = lane >> 4, chunk = lane & 15;   // staging map (4 rows x 256 B per q)
    const int quad = lane & 15, sl = lane >> 4;      // compute map (16 quads x 4 subgroups)

    const float* xh = x + (size_t)b * T_ * C_ + h * 64;

    // stage rows row0..row0+31 into ring slot (8 DMA, 1 KB each)
    auto stageChunk = [&](const int slot, const int row0) {
        float* dst = smem + slot * (CH * 64);
        #pragma unroll
        for (int q = 0; q < 8; ++q) {
            const float* src = xh + (size_t)(row0 + 4 * q + qrow) * C_ + chunk * 4;
            __builtin_amdgcn_global_load_lds(
                (const __attribute__((address_space(1))) uint32_t*)src,
                (__attribute__((address_space(3))) uint32_t*)(dst + q * 256),
                16, 0, 0);
        }
    };

    // ---- prologue: DMA C_{-1} (slot 2, skip if t<0) and C_0 (slot 0)
    if (ts > 0) stageChunk(2, ts - CH);
    stageChunk(0, ts);

    // softmax(w[h]) under the DMA (block-uniform -> s_load + uniform VALU)
    float wv[KW];
    {
        float v[KW]; float m = -1e30f;
        #pragma unroll
        for (int k = 0; k < KW; ++k) { v[k] = w[h * KW + k]; m = fmaxf(m, v[k]); }
        float s = 0.f;
        #pragma unroll
        for (int k = 0; k < KW; ++k) { v[k] = __expf(v[k] - m); s += v[k]; }
        const float inv = 1.f / s;
        #pragma unroll
        for (int j = 0; j < KW; ++j) wv[j] = rfl(v[KW - 1 - j] * inv);  // reversed -> SGPR
    }

    if (ts == 0) {                            // zero-fill slot 2 (rows t<0)
        f32x4* s4 = (f32x4*)(smem + 2 * (CH * 64));
        #pragma unroll
        for (int k = 0; k < 8; ++k) s4[k * 64 + lane] = (f32x4)0.f;
    }

    int slotA = 2, slotB = 0, slotN = 1;      // C_{j-1}, C_j, C_{j+1}

    #pragma unroll 1
    for (int j = 0; j < NTILE; ++j) {
        if (j + 1 < NTILE) stageChunk(slotN, ts + CH * (j + 1));
        __builtin_amdgcn_sched_barrier(0);

        // counted wait: guarantee C_{j-1},C_j landed; keep newer DMA/stores in flight
        if (j == 0)
            asm volatile("s_waitcnt vmcnt(8) lgkmcnt(0)" ::: "memory");
        else if (j == NTILE - 1)
            asm volatile("s_waitcnt vmcnt(8)" ::: "memory");
        else
            asm volatile("s_waitcnt vmcnt(16)" ::: "memory");
        __builtin_amdgcn_sched_barrier(0);

        // ---- compute tile j: thread rows t0+8*sl .. +7, window rows -30..+7
        const f32x4* pa = (const f32x4*)(smem + slotA * (CH * 64));
        const f32x4* pb = (const f32x4*)(smem + slotB * (CH * 64));

        f32x4 acc[TT];
        #pragma unroll
        for (int i = 0; i < TT; ++i) acc[i] = (f32x4)0.f;

        #pragma unroll
        for (int sr = 0; sr < TT + HALO; ++sr) {       // window row r = 8*sl+2+sr (2..63)
            const int r = 8 * sl + 2 + sr;
            const f32x4 v = (r < CH) ? pa[r * 16 + quad] : pb[(r - CH) * 16 + quad];
            const int ilo = (sr - HALO < 0) ? 0 : sr - HALO;
            const int ihi = (sr < TT - 1) ? sr : TT - 1;
            #pragma unroll
            for (int i = ilo; i <= ihi; ++i) {         // weight idx i+30-sr, static
                acc[i] += wv[i + HALO - sr] * v;
            }
        }

        const int t0 = ts + CH * j;
        f32x4* po = (f32x4*)out + ((size_t)b * T_ + t0 + 8 * sl) * C4 + h * 16 + quad;
        #pragma unroll
        for (int i = 0; i < TT; ++i)
            __builtin_nontemporal_store(acc[i], po + (size_t)i * C4);

        const int tmp = slotA; slotA = slotB; slotB = slotN; slotN = tmp;   // rotate ring
    }
}

extern "C" void kernel_launch(void* const* d_in, const int* in_sizes, int n_in,
                              void* d_out, int out_size, void* d_ws, size_t ws_size,
                              hipStream_t stream) {
    const float* x = (const float*)d_in[0];
    const float* w = (const float*)d_in[1];
    float* out = (float*)d_out;

    dim3 grid(H_, T_ / SEG, B_);   // (16, 4, 16) = 1024 single-wave blocks = 4.0/CU
    hipLaunchKernelGGL(lconv_kernel, grid, dim3(TPB), 0, stream, x, w, out);
}